// Round 1
// baseline (3221.554 us; speedup 1.0000x reference)
//
#include <hip/hip_runtime.h>
#include <math.h>

#define B 32
#define T 32
#define I_DIM 256
#define O_DIM 256
#define H_DIM 512
#define HS 64
#define MS 2048
#define NH 4
#define G4H 2048       // 4*H
#define NCOL 516       // used head cols: 4 heads * (64 rk + 64 wk + 1 strength)
#define NCOLP 520      // padded
#define CHUNK 128
#define NCH 16         // MS / CHUNK

__device__ __forceinline__ float sigm(float x){ return 1.0f/(1.0f+__expf(-x)); }

// Tiled transpose: src is N rows x K cols, dst is K rows x N cols.
__global__ __launch_bounds__(256) void k_transpose_t(float* __restrict__ dst,
                                                     const float* __restrict__ src,
                                                     int N, int K){
  __shared__ float tile[32][33];
  int jb = blockIdx.x*32, kb = blockIdx.y*32;
  int tj = threadIdx.x & 31, tk = threadIdx.x >> 5;   // 32 x 8
  #pragma unroll
  for (int p = 0; p < 4; ++p){
    int j = jb + tk + p*8, k = kb + tj;
    if (j < N && k < K) tile[tk + p*8][tj] = src[j*K + k];
  }
  __syncthreads();
  #pragma unroll
  for (int p = 0; p < 4; ++p){
    int k = kb + tk + p*8, j = jb + tj;
    if (j < N && k < K) dst[k*N + j] = tile[tj][tk + p*8];
  }
}

// Gather+transpose used W_head rows -> wt_hd[k*NCOLP + col]
__global__ __launch_bounds__(256) void k_gather_head(float* __restrict__ dst,
                                                     const float* __restrict__ W_head){
  int tid = blockIdx.x*256 + threadIdx.x;
  if (tid >= 512*NCOLP) return;
  int k = tid / NCOLP, col = tid % NCOLP;
  float v = 0.f;
  if (col < NCOL){
    int n = col/129, c = col%129;
    v = W_head[(n*2115 + c)*512 + k];
  }
  dst[tid] = v;
}

// gates partial GEMM: grid (32 o-tiles of 64, 4 k-chunks of 256), 256 thr
__global__ __launch_bounds__(256) void k_gates(
    const float* __restrict__ x, const float* __restrict__ wt_ih,
    const float* __restrict__ wt_hh, const float* __restrict__ hbuf,
    const float* __restrict__ readb, float* __restrict__ gp, int t)
{
  __shared__ float A[32*257];
  int nt = blockIdx.x, kc = blockIdx.y;
  int k0 = kc*256;
  for (int idx = threadIdx.x; idx < 32*256; idx += 256){
    int b = idx >> 8, k = idx & 255;
    int kg = k0 + k;
    float v;
    if (kg < I_DIM)        v = x[(b*T + t)*I_DIM + kg];
    else if (kg < 512)     v = readb[b*256 + (kg - 256)];
    else                   v = hbuf[b*H_DIM + (kg - 512)];
    A[b*257 + k] = v;
  }
  __syncthreads();
  int b = threadIdx.x & 31;
  int osub = threadIdx.x >> 5;
  int o = nt*64 + osub*8;
  const float* W = (k0 < 512) ? (wt_ih + k0*G4H) : (wt_hh + (k0-512)*G4H);
  float acc[8];
  #pragma unroll
  for (int i=0;i<8;++i) acc[i] = 0.f;
  const float* Ab = A + b*257;
  for (int k = 0; k < 256; ++k){
    float a = Ab[k];
    const float4* w4 = (const float4*)(W + k*G4H + o);
    float4 w0 = w4[0], w1 = w4[1];
    acc[0] += a*w0.x; acc[1] += a*w0.y; acc[2] += a*w0.z; acc[3] += a*w0.w;
    acc[4] += a*w1.x; acc[5] += a*w1.y; acc[6] += a*w1.z; acc[7] += a*w1.w;
  }
  float* g = gp + kc*(B*G4H) + b*G4H + o;
  #pragma unroll
  for (int i=0;i<8;++i) g[i] = acc[i];
}

// LSTM elementwise + head projection (used cols only). grid: 32 blocks (one per b)
__global__ __launch_bounds__(256) void k_lstm_hp(
    const float* __restrict__ gp, const float* __restrict__ b_ih,
    const float* __restrict__ b_hh, const float* __restrict__ wt_hd,
    const float* __restrict__ b_head, float* __restrict__ hbuf,
    float* __restrict__ cbuf, float* __restrict__ hhist,
    float* __restrict__ hp, int t)
{
  __shared__ float hl[512];
  int b = blockIdx.x;
  for (int j = threadIdx.x; j < 512; j += 256){
    float gi = b_ih[j]      + b_hh[j];
    float gf = b_ih[j+512]  + b_hh[j+512];
    float gg = b_ih[j+1024] + b_hh[j+1024];
    float go = b_ih[j+1536] + b_hh[j+1536];
    #pragma unroll
    for (int kc = 0; kc < 4; ++kc){
      const float* g = gp + kc*(B*G4H) + b*G4H;
      gi += g[j]; gf += g[j+512]; gg += g[j+1024]; go += g[j+1536];
    }
    float c = sigm(gf)*cbuf[b*512+j] + sigm(gi)*tanhf(gg);
    float h = sigm(go)*tanhf(c);
    cbuf[b*512+j] = c;
    hbuf[b*512+j] = h;
    hhist[(t*B + b)*512 + j] = h;
    hl[j] = h;
  }
  __syncthreads();
  for (int col = threadIdx.x; col < NCOLP; col += 256){
    float acc = 0.f;
    if (col < NCOL){
      int n = col/129, c = col%129;
      acc = b_head[n*2115 + c];
      for (int k = 0; k < 512; ++k) acc += hl[k] * wt_hd[k*NCOLP + col];
    }
    hp[b*NCOLP + col] = acc;
  }
}

// attention pass 1: scores, chunk softmax partials, partial reads.
// grid (b=32, ch=16), 256 thr
__global__ __launch_bounds__(256) void k_scores(
    const float* __restrict__ mem, const float* __restrict__ hp,
    float* __restrict__ sw, float* __restrict__ part, float* __restrict__ pread)
{
  __shared__ float keys[8*64];
  __shared__ float mc[CHUNK*65];
  __shared__ float sc[8*CHUNK];
  __shared__ float red[8*32];
  __shared__ float cmx[8];
  int b = blockIdx.x, ch = blockIdx.y;
  for (int idx = threadIdx.x; idx < 512; idx += 256){
    int kk = idx >> 6, e = idx & 63;
    int n = kk & 3;
    int c = (kk >= 4) ? (64 + e) : e;
    keys[kk*64 + e] = hp[b*NCOLP + n*129 + c];
  }
  for (int idx = threadIdx.x; idx < CHUNK*64; idx += 256){
    int m = idx >> 6, e = idx & 63;
    mc[m*65 + e] = mem[(b*MS + ch*CHUNK + m)*64 + e];
  }
  __syncthreads();
  {
    int m = threadIdx.x & 127, kp = threadIdx.x >> 7;
    #pragma unroll
    for (int q = 0; q < 4; ++q){
      int kk = kp*4 + q;
      float s = 0.f;
      const float* mrow = mc + m*65;
      const float* kv = keys + kk*64;
      for (int e = 0; e < 64; ++e) s += mrow[e]*kv[e];
      s *= 0.125f;
      sc[kk*128 + m] = s;
      if (kp) sw[(b*4 + (kk-4))*MS + ch*CHUNK + m] = s;
    }
  }
  __syncthreads();
  {
    int kk = threadIdx.x >> 5, j = threadIdx.x & 31;
    float mx = sc[kk*128+j];
    mx = fmaxf(mx, sc[kk*128+j+32]);
    mx = fmaxf(mx, sc[kk*128+j+64]);
    mx = fmaxf(mx, sc[kk*128+j+96]);
    red[kk*32+j] = mx;
  }
  __syncthreads();
  if (threadIdx.x < 8){
    float mx = red[threadIdx.x*32];
    for (int j=1;j<32;++j) mx = fmaxf(mx, red[threadIdx.x*32+j]);
    cmx[threadIdx.x] = mx;
  }
  __syncthreads();
  {
    int kk = threadIdx.x >> 5, j = threadIdx.x & 31;
    float m0 = cmx[kk];
    float se = 0.f;
    #pragma unroll
    for (int i=0;i<4;++i){
      int m = j + i*32;
      float e0 = __expf(sc[kk*128+m] - m0);
      se += e0;
      if (kk < 4) sc[kk*128+m] = e0;   // keep unnormalized exp for partial read
    }
    red[kk*32+j] = se;
  }
  __syncthreads();
  if (threadIdx.x < 8){
    float s = 0.f;
    for (int j=0;j<32;++j) s += red[threadIdx.x*32+j];
    int kk = threadIdx.x;
    part[((b*NCH+ch)*8 + kk)*2]     = cmx[kk];
    part[((b*NCH+ch)*8 + kk)*2 + 1] = s;
  }
  {
    int n = threadIdx.x >> 6, e = threadIdx.x & 63;
    float pr = 0.f;
    for (int m = 0; m < CHUNK; ++m) pr += sc[n*128+m] * mc[m*65+e];
    pread[((b*NCH+ch)*4 + n)*64 + e] = pr;
  }
}

// attention pass 2: merge softmax, finalize read, update mem. grid (32,16)
__global__ __launch_bounds__(256) void k_update(
    float* __restrict__ mem, const float* __restrict__ hp,
    const float* __restrict__ sw, const float* __restrict__ part,
    const float* __restrict__ pread, float* __restrict__ readb,
    float* __restrict__ rhist, int t)
{
  __shared__ float gm[8], dn[8];
  __shared__ float wk[4*64];
  __shared__ float st[4];
  __shared__ float ww[4*128];
  int b = blockIdx.x, ch = blockIdx.y;
  if (threadIdx.x < 8){
    int kk = threadIdx.x;
    float mx = -1e30f;
    for (int c = 0; c < NCH; ++c) mx = fmaxf(mx, part[((b*NCH+c)*8+kk)*2]);
    float d = 0.f;
    for (int c = 0; c < NCH; ++c)
      d += part[((b*NCH+c)*8+kk)*2+1] * __expf(part[((b*NCH+c)*8+kk)*2] - mx);
    gm[kk] = mx; dn[kk] = d;
  }
  {
    int n = threadIdx.x >> 6, e = threadIdx.x & 63;
    wk[n*64+e] = hp[b*NCOLP + n*129 + 64 + e];
  }
  if (threadIdx.x < 4) st[threadIdx.x] = sigm(hp[b*NCOLP + threadIdx.x*129 + 128]);
  __syncthreads();
  for (int idx = threadIdx.x; idx < 512; idx += 256){
    int n = idx >> 7, m = idx & 127;
    float s = sw[(b*4+n)*MS + ch*CHUNK + m];
    ww[n*128+m] = __expf(s - gm[4+n]) / dn[4+n] * st[n];
  }
  __syncthreads();
  if (ch == 0){
    int n = threadIdx.x >> 6, e = threadIdx.x & 63;
    float r = 0.f;
    for (int c = 0; c < NCH; ++c){
      float cm = part[((b*NCH+c)*8+n)*2];
      r += pread[((b*NCH+c)*4+n)*64+e] * __expf(cm - gm[n]);
    }
    r /= dn[n];
    readb[b*256 + n*64 + e] = r;
    rhist[(t*B + b)*256 + n*64 + e] = r;
  }
  {
    int ms = threadIdx.x >> 6, e = threadIdx.x & 63;
    for (int it = 0; it < 32; ++it){
      int m = it*4 + ms;
      float add = ww[0*128+m]*wk[0*64+e] + ww[1*128+m]*wk[1*64+e]
                + ww[2*128+m]*wk[2*64+e] + ww[3*128+m]*wk[3*64+e];
      int gi = (b*MS + ch*CHUNK + m)*64 + e;
      mem[gi] += add;
    }
  }
}

// final output GEMM over all timesteps: rows = b*T+t (1024), N=256, K=768
__global__ __launch_bounds__(256) void k_out(
    const float* __restrict__ hhist, const float* __restrict__ rhist,
    const float* __restrict__ wt_out, const float* __restrict__ b_out,
    float* __restrict__ out)
{
  __shared__ float A[32*257];
  int nt = blockIdx.x;   // 4 o-tiles of 64
  int mt = blockIdx.y;   // 32 row tiles of 32
  int rl = threadIdx.x & 31, osub = threadIdx.x >> 5;
  int o = nt*64 + osub*8;
  float acc[8];
  #pragma unroll
  for (int i=0;i<8;++i) acc[i] = 0.f;
  for (int kc = 0; kc < 3; ++kc){
    __syncthreads();
    for (int idx = threadIdx.x; idx < 32*256; idx += 256){
      int r = idx >> 8, k = idx & 255;
      int kg = kc*256 + k;
      int row = mt*32 + r;
      int bb = row >> 5, tt = row & 31;
      float v;
      if (kg < 512) v = hhist[(tt*B + bb)*512 + kg];
      else          v = rhist[(tt*B + bb)*256 + (kg - 512)];
      A[r*257 + k] = v;
    }
    __syncthreads();
    const float* Ar = A + rl*257;
    for (int k = 0; k < 256; ++k){
      float a = Ar[k];
      const float4* w4 = (const float4*)(wt_out + (kc*256+k)*O_DIM + o);
      float4 w0 = w4[0], w1 = w4[1];
      acc[0] += a*w0.x; acc[1] += a*w0.y; acc[2] += a*w0.z; acc[3] += a*w0.w;
      acc[4] += a*w1.x; acc[5] += a*w1.y; acc[6] += a*w1.z; acc[7] += a*w1.w;
    }
  }
  int row = mt*32 + rl;
  #pragma unroll
  for (int i=0;i<8;++i) out[row*O_DIM + o + i] = acc[i] + b_out[o+i];
}

extern "C" void kernel_launch(void* const* d_in, const int* in_sizes, int n_in,
                              void* d_out, int out_size, void* d_ws, size_t ws_size,
                              hipStream_t stream)
{
  const float* x      = (const float*)d_in[0];
  const float* W_ih   = (const float*)d_in[1];
  const float* W_hh   = (const float*)d_in[2];
  const float* b_ih   = (const float*)d_in[3];
  const float* b_hh   = (const float*)d_in[4];
  const float* W_head = (const float*)d_in[5];
  const float* b_head = (const float*)d_in[6];
  const float* W_out  = (const float*)d_in[7];
  const float* b_out  = (const float*)d_in[8];

  float* out = (float*)d_out;
  float* MEM = out + B*T*O_DIM;        // mem output slot, used as live state
  float* HF  = MEM + B*MS*HS;          // final h slot, used as live state
  float* CF  = HF + B*H_DIM;           // final c slot, used as live state

  float* ws     = (float*)d_ws;
  float* WT_IH  = ws;                    // 512*2048
  float* WT_HH  = WT_IH  + 512*2048;     // 512*2048
  float* WT_HD  = WT_HH  + 512*2048;     // 512*520
  float* WT_OUT = WT_HD  + 512*NCOLP;    // 768*256
  float* GP     = WT_OUT + 768*256;      // 4*B*2048
  float* HP     = GP     + 4*B*G4H;      // B*520
  float* SW     = HP     + B*NCOLP;      // B*4*2048
  float* PART   = SW     + B*4*MS;       // B*16*8*2
  float* PREAD  = PART   + B*NCH*16;     // B*16*4*64
  float* READ   = PREAD  + B*NCH*4*64;   // B*256
  float* HHIST  = READ   + B*256;        // T*B*512
  float* RHIST  = HHIST  + T*B*512;      // T*B*256

  hipMemsetAsync(MEM, 0, (size_t)(B*MS*HS + 2*B*H_DIM)*sizeof(float), stream);
  hipMemsetAsync(READ, 0, (size_t)(B*256)*sizeof(float), stream);

  k_transpose_t<<<dim3(2048/32, 512/32), 256, 0, stream>>>(WT_IH, W_ih, 2048, 512);
  k_transpose_t<<<dim3(2048/32, 512/32), 256, 0, stream>>>(WT_HH, W_hh, 2048, 512);
  k_transpose_t<<<dim3(256/32, 768/32), 256, 0, stream>>>(WT_OUT, W_out, 256, 768);
  k_gather_head<<<(512*NCOLP + 255)/256, 256, 0, stream>>>(WT_HD, W_head);

  for (int t = 0; t < T; ++t){
    k_gates  <<<dim3(32, 4), 256, 0, stream>>>(x, WT_IH, WT_HH, HF, READ, GP, t);
    k_lstm_hp<<<32,          256, 0, stream>>>(GP, b_ih, b_hh, WT_HD, b_head,
                                               HF, CF, HHIST, HP, t);
    k_scores <<<dim3(32,16), 256, 0, stream>>>(MEM, HP, SW, PART, PREAD);
    k_update <<<dim3(32,16), 256, 0, stream>>>(MEM, HP, SW, PART, PREAD, READ, RHIST, t);
  }
  k_out<<<dim3(4, 32), 256, 0, stream>>>(HHIST, RHIST, WT_OUT, b_out, out);
}